// Round 2
// baseline (282.132 us; speedup 1.0000x reference)
//
#include <hip/hip_runtime.h>
#include <hip/hip_bf16.h>

#define NC 30
#define WIDTH 64
#define DD 32
#define BATCH_N 1048576

typedef __bf16 bf16x8 __attribute__((ext_vector_type(8)));
typedef __bf16 bf16x4 __attribute__((ext_vector_type(4)));
typedef float f32x4 __attribute__((ext_vector_type(4)));

__device__ __forceinline__ bf16x8 pack_bf8(float4 a, float4 b) {
    bf16x8 r;
    r[0] = (__bf16)a.x; r[1] = (__bf16)a.y; r[2] = (__bf16)a.z; r[3] = (__bf16)a.w;
    r[4] = (__bf16)b.x; r[5] = (__bf16)b.y; r[6] = (__bf16)b.z; r[7] = (__bf16)b.w;
    return r;
}

// ---------------- Stage 1: hypernetwork (Wt, UtT/64, Bt, wu/64) ----------------
// grid 16 x 128: thread j computes Wt[j] and Ut[j]; wu via intra-wave shuffle.
// Ut and wu are pre-scaled by 1/64 (exact power of two) so the main kernel's
// epilogue needs no per-element inv multiplies.
__global__ void hyper_rows(
    const float* __restrict__ t,
    const float* __restrict__ Wc, const float* __restrict__ Wls,
    const float* __restrict__ Ww, const float* __restrict__ Wb,
    const float* __restrict__ Uc, const float* __restrict__ Uls,
    const float* __restrict__ Uw, const float* __restrict__ Ub,
    const float* __restrict__ Bc, const float* __restrict__ Bls,
    const float* __restrict__ Bw, const float* __restrict__ Bb,
    float* __restrict__ outWt, float* __restrict__ outUtT,
    float* __restrict__ outBt, float* __restrict__ outwu)
{
    __shared__ float phiW[NC], phiU[NC], phiB[NC];
    const float tv = t[0];
    const int tid = threadIdx.x;
    if (tid < NC) {
        float dW = fabsf(tv - Wc[tid]) * __expf(-Wls[tid]);
        phiW[tid] = __expf(-dW * dW);
        float dU = fabsf(tv - Uc[tid]) * __expf(-Uls[tid]);
        phiU[tid] = __expf(-dU * dU);
        float dB = fabsf(tv - Bc[tid]) * __expf(-Bls[tid]);
        phiB[tid] = __expf(-dB * dB);
    }
    __syncthreads();
    const int j = blockIdx.x * blockDim.x + tid;   // 0..2047
    float aw = Wb[j];
    float au = Ub[j];
    #pragma unroll
    for (int k = 0; k < NC; ++k) {
        aw += phiW[k] * Ww[j * NC + k];
        au += phiU[k] * Uw[j * NC + k];
    }
    outWt[j] = aw;                       // Wt row-major (64 x 32)
    const int w = j >> 5, i = j & 31;
    outUtT[i * WIDTH + w] = au * 0.015625f;   // Ut^T / 64  (32 x 64)

    // wu[w]/64 = (1/64) * sum_i Wt[w,i]*Ut[w,i]
    float p = aw * au;
    #pragma unroll
    for (int off = 1; off < 32; off <<= 1) p += __shfl_xor(p, off, 64);
    if ((tid & 31) == 0) outwu[w] = p * 0.015625f;

    if (blockIdx.x == 0 && tid < WIDTH) {
        float ab = Bb[tid];
        #pragma unroll
        for (int k = 0; k < NC; ++k) ab += phiB[k] * Bw[tid * NC + k];
        outBt[tid] = ab;
    }
}

// ---------------- Stage 2: MFMA main kernel (swapped-operand layout) ----------------
// Per wave: 8 iterations of a 16-row batch tile.
//   S^T(64x16) = Wt @ z^T    -> 4x mfma(bW, aZ): C-frag has batch = l15 (lane-local),
//                               width-in-tile = quad*4+r  -> widths 16*t4+4*quad+r
//   h = tanh(S + Bt): each lane's 4 r-values are CONTIGUOUS widths -> one ds_write_b64
//     per t4 (4 writes/iter vs 16 scalar b16 before)
//   trace partial is a single scalar per lane (one batch row) -> 2 shuffles (was 16)
//   dz(16x32) = h(16x64) @ (Ut/64)  -> 2 ds_read_b128 + 4x mfma, unchanged C layout
__global__ __launch_bounds__(256, 4) void cnf_main(
    const float* __restrict__ z,
    const float* __restrict__ Wt,   // 64 x 32
    const float* __restrict__ UtT,  // 32 x 64, pre-scaled by 1/64
    const float* __restrict__ Bt, const float* __restrict__ wu,  // wu pre-scaled 1/64
    float* __restrict__ dz, float* __restrict__ dlogp)
{
    __shared__ __bf16 hbuf[4][16][72];   // stride 72 bf16 = 144 B: 16B-aligned rows, <=2-way banks
    const int tid  = threadIdx.x;
    const int wave = tid >> 6;
    const int lane = tid & 63;
    const int l15  = lane & 15;
    const int quad = lane >> 4;          // 0..3
    __bf16 (*hl)[72] = hbuf[wave];

    // ---- preload weight fragments (wave-invariant across the loop) ----
    bf16x8 bW[4];                        // A-frag of Wt, m-tile t4: A[m][k]=Wt[t4*16+m][k]
    #pragma unroll
    for (int t4 = 0; t4 < 4; ++t4) {
        const float4* p = (const float4*)(Wt + (t4 * 16 + l15) * DD + quad * 8);
        bW[t4] = pack_bf8(p[0], p[1]);
    }
    bf16x8 bU[2][2];                     // [k-chunk c][n-tile t2]: B[k2][i]=UtT[i][k2]
    #pragma unroll
    for (int c = 0; c < 2; ++c)
        #pragma unroll
        for (int t2 = 0; t2 < 2; ++t2) {
            const float4* p = (const float4*)(UtT + (t2 * 16 + l15) * WIDTH + c * 32 + quad * 8);
            bU[c][t2] = pack_bf8(p[0], p[1]);
        }
    // per-lane width set: w(t4,r) = t4*16 + quad*4 + r
    //   bt2[i] = 2*log2(e)*Bt[w]  (feeds exp2 directly)
    //   wu4[i] = 4*wu[w]/64       (part += u*(1-u) * wu4 == (1-h^2)*wu/64)
    const float TWO_LOG2E = 2.8853900817779268f;
    float bt2[16], wu4[16];
    #pragma unroll
    for (int t4 = 0; t4 < 4; ++t4)
        #pragma unroll
        for (int r = 0; r < 4; ++r) {
            const int wdx = t4 * 16 + quad * 4 + r;
            bt2[t4 * 4 + r] = TWO_LOG2E * Bt[wdx];
            wu4[t4 * 4 + r] = 4.0f * wu[wdx];
        }

    const size_t gw = (size_t)blockIdx.x * 4 + wave;     // 0..8191, 128 rows each
    const float* zp = z + (gw * 128 + l15) * DD + quad * 8;

    float4 za = ((const float4*)zp)[0];
    float4 zb = ((const float4*)zp)[1];
    const f32x4 zero = {0.f, 0.f, 0.f, 0.f};

    for (int it = 0; it < 8; ++it) {
        float4 na = {0,0,0,0}, nb = {0,0,0,0};
        if (it < 7) {                                    // wave-uniform branch
            const float4* np = (const float4*)(zp + 16 * DD);
            na = np[0]; nb = np[1];
        }

        // ---- GEMM 1 (swapped): S^T = Wt @ z^T ----
        bf16x8 aZ = pack_bf8(za, zb);                    // as B-frag: B[k][n]=z[n][k]
        f32x4 accS[4];
        #pragma unroll
        for (int t4 = 0; t4 < 4; ++t4)
            accS[t4] = __builtin_amdgcn_mfma_f32_16x16x32_bf16(bW[t4], aZ, zero, 0, 0, 0);

        // ---- epilogue: tanh + trace partial + packed h -> LDS ----
        // lane holds S[b = base+l15][w = 16*t4+4*quad+r] -> batch row is lane-local
        float part = 0.f;
        #pragma unroll
        for (int t4 = 0; t4 < 4; ++t4) {
            bf16x4 hp;
            #pragma unroll
            for (int r = 0; r < 4; ++r) {
                const float f = fmaf(accS[t4][r], TWO_LOG2E, bt2[t4 * 4 + r]);
                const float e = exp2f(f);                        // e^(2s+2b), v_exp_f32
                const float u = __builtin_amdgcn_rcpf(e + 1.0f);
                const float h = fmaf(-2.0f, u, 1.0f);            // tanh(s+b)
                part = fmaf(fmaf(-u, u, u), wu4[t4 * 4 + r], part); // += (1-h^2)*wu/64
                hp[r] = (__bf16)h;
            }
            // widths 16*t4+4*quad .. +3 are contiguous: one 8B write
            *(bf16x4*)(&hl[l15][t4 * 16 + quad * 4]) = hp;
        }

        // ---- GEMM 2: dz = h @ (Ut/64) ----  (A-frag: contiguous 16B per lane)
        bf16x8 aH0 = *(const bf16x8*)&hl[l15][quad * 8];        // k = quad*8+j
        bf16x8 aH1 = *(const bf16x8*)&hl[l15][32 + quad * 8];   // k = 32+quad*8+j
        f32x4 accD[2];
        #pragma unroll
        for (int t2 = 0; t2 < 2; ++t2) {
            f32x4 c0 = __builtin_amdgcn_mfma_f32_16x16x32_bf16(aH0, bU[0][t2], zero, 0, 0, 0);
            accD[t2]  = __builtin_amdgcn_mfma_f32_16x16x32_bf16(aH1, bU[1][t2], c0, 0, 0, 0);
        }

        // ---- trace: reduce across the 4 quads only (batch row = l15 fixed) ----
        part += __shfl_xor(part, 16, 64);
        part += __shfl_xor(part, 32, 64);

        const size_t row0 = gw * 128 + (size_t)it * 16;
        if (quad == 0) dlogp[row0 + l15] = -part;      // 16 lanes, 64B coalesced

        // ---- dz stores (C-layout, 64B-coalesced per 16-lane group) ----
        #pragma unroll
        for (int t2 = 0; t2 < 2; ++t2)
            #pragma unroll
            for (int r = 0; r < 4; ++r)
                dz[(row0 + quad * 4 + r) * DD + t2 * 16 + l15] = accD[t2][r];

        za = na; zb = nb;
        zp += 16 * DD;
    }
}

extern "C" void kernel_launch(void* const* d_in, const int* in_sizes, int n_in,
                              void* d_out, int out_size, void* d_ws, size_t ws_size,
                              hipStream_t stream)
{
    const float* t   = (const float*)d_in[0];
    const float* z   = (const float*)d_in[1];
    // d_in[2] = logp_z: unused by the reference outputs
    const float* Wc  = (const float*)d_in[3];
    const float* Wls = (const float*)d_in[4];
    const float* Ww  = (const float*)d_in[5];
    const float* Wb  = (const float*)d_in[6];
    const float* Uc  = (const float*)d_in[7];
    const float* Uls = (const float*)d_in[8];
    const float* Uw  = (const float*)d_in[9];
    const float* Ub  = (const float*)d_in[10];
    const float* Bc  = (const float*)d_in[11];
    const float* Bls = (const float*)d_in[12];
    const float* Bw  = (const float*)d_in[13];
    const float* Bb  = (const float*)d_in[14];

    float* wsWt  = (float*)d_ws;         // 2048  (Wt 64x32 row-major)
    float* wsUtT = wsWt + 2048;          // 2048  (Ut^T/64, 32x64)
    float* wsBt  = wsUtT + 2048;         // 64
    float* wswu  = wsBt + 64;            // 64   (wu/64)

    hyper_rows<<<16, 128, 0, stream>>>(t, Wc, Wls, Ww, Wb, Uc, Uls, Uw, Ub,
                                       Bc, Bls, Bw, Bb, wsWt, wsUtT, wsBt, wswu);

    float* dz = (float*)d_out;
    float* dlogp = dz + (size_t)BATCH_N * DD;
    cnf_main<<<2048, 256, 0, stream>>>(z, wsWt, wsUtT, wsBt, wswu, dz, dlogp);
}

// Round 8
// 281.844 us; speedup vs baseline: 1.0010x; 1.0010x over previous
//
#include <hip/hip_runtime.h>
#include <hip/hip_bf16.h>

#define NC 30
#define WIDTH 64
#define DD 32
#define BATCH_N 1048576

typedef __bf16 bf16x8 __attribute__((ext_vector_type(8)));
typedef __bf16 bf16x4 __attribute__((ext_vector_type(4)));
typedef float f32x4 __attribute__((ext_vector_type(4)));
typedef unsigned int uint32x2 __attribute__((ext_vector_type(2)));
typedef unsigned int uint32x4 __attribute__((ext_vector_type(4)));

__device__ __forceinline__ bf16x8 pack_bf8(float4 a, float4 b) {
    bf16x8 r;
    r[0] = (__bf16)a.x; r[1] = (__bf16)a.y; r[2] = (__bf16)a.z; r[3] = (__bf16)a.w;
    r[4] = (__bf16)b.x; r[5] = (__bf16)b.y; r[6] = (__bf16)b.z; r[7] = (__bf16)b.w;
    return r;
}

// ---------------- Stage 1: hypernetwork (Wt, UtT/64, Bt, wu/64) ----------------
__global__ void hyper_rows(
    const float* __restrict__ t,
    const float* __restrict__ Wc, const float* __restrict__ Wls,
    const float* __restrict__ Ww, const float* __restrict__ Wb,
    const float* __restrict__ Uc, const float* __restrict__ Uls,
    const float* __restrict__ Uw, const float* __restrict__ Ub,
    const float* __restrict__ Bc, const float* __restrict__ Bls,
    const float* __restrict__ Bw, const float* __restrict__ Bb,
    float* __restrict__ outWt, float* __restrict__ outUtT,
    float* __restrict__ outBt, float* __restrict__ outwu)
{
    __shared__ float phiW[NC], phiU[NC], phiB[NC];
    const float tv = t[0];
    const int tid = threadIdx.x;
    if (tid < NC) {
        float dW = fabsf(tv - Wc[tid]) * __expf(-Wls[tid]);
        phiW[tid] = __expf(-dW * dW);
        float dU = fabsf(tv - Uc[tid]) * __expf(-Uls[tid]);
        phiU[tid] = __expf(-dU * dU);
        float dB = fabsf(tv - Bc[tid]) * __expf(-Bls[tid]);
        phiB[tid] = __expf(-dB * dB);
    }
    __syncthreads();
    const int j = blockIdx.x * blockDim.x + tid;   // 0..2047
    float aw = Wb[j];
    float au = Ub[j];
    #pragma unroll
    for (int k = 0; k < NC; ++k) {
        aw += phiW[k] * Ww[j * NC + k];
        au += phiU[k] * Uw[j * NC + k];
    }
    outWt[j] = aw;                       // Wt row-major (64 x 32)
    const int w = j >> 5, i = j & 31;
    outUtT[i * WIDTH + w] = au * 0.015625f;   // Ut^T / 64  (32 x 64)

    // wu[w]/64 = (1/64) * sum_i Wt[w,i]*Ut[w,i]
    float p = aw * au;
    #pragma unroll
    for (int off = 1; off < 32; off <<= 1) p += __shfl_xor(p, off, 64);
    if ((tid & 31) == 0) outwu[w] = p * 0.015625f;

    if (blockIdx.x == 0 && tid < WIDTH) {
        float ab = Bb[tid];
        #pragma unroll
        for (int k = 0; k < NC; ++k) ab += phiB[k] * Bw[tid * NC + k];
        outBt[tid] = ab;
    }
}

// ---------------- Stage 2: MFMA main kernel (zero-LDS, permlane exchange) ----------------
// Per wave: 8 iterations of a 16-row batch tile.
//   S^T(64x16) = Wt @ z^T   -> 4x mfma(bW, aZ): batch = l15 (lane-local),
//                              width = 16*t4 + 4*quad + r
//   h = tanh(S+Bt), packed to bf16x4 per t4 (2 dwords)
//   h quad-exchange IN REGISTERS (algebra HW-validated by round 5's pre-timing pass):
//     permlane32_swap(A,B): [0] = [A.lo32|B.lo32], [1] = [A.hi32|B.hi32]
//     permlane16_swap(A,B): [0] rows = [A.r0,B.r0,A.r2,B.r2], [1] rows = [A.r1,B.r1,A.r3,B.r3]
//     {w16a[0], w16b[0], w16a[1], w16b[1]} = h[b=l15][w = 8*quad .. 8*quad+7]  == GEMM2 B-frag
//   dz^T = Ut^T @ h^T       -> mfma(bU, aH): lane gets 4 contiguous dz cols -> float4 store
//   trace reduce: __shfl_xor 16/32 (HW-proven in the round-2 passing kernel)
__global__ __launch_bounds__(256, 4) void cnf_main(
    const float* __restrict__ z,
    const float* __restrict__ Wt,   // 64 x 32
    const float* __restrict__ UtT,  // 32 x 64, pre-scaled by 1/64
    const float* __restrict__ Bt, const float* __restrict__ wu,  // wu pre-scaled 1/64
    float* __restrict__ dz, float* __restrict__ dlogp)
{
    const int tid  = threadIdx.x;
    const int wave = tid >> 6;
    const int lane = tid & 63;
    const int l15  = lane & 15;
    const int quad = lane >> 4;          // 0..3

    // ---- preload weight fragments (wave-invariant across the loop) ----
    bf16x8 bW[4];                        // A-frag of Wt, m-tile t4: A[m][k]=Wt[t4*16+m][k]
    #pragma unroll
    for (int t4 = 0; t4 < 4; ++t4) {
        const float4* p = (const float4*)(Wt + (t4 * 16 + l15) * DD + quad * 8);
        bW[t4] = pack_bf8(p[0], p[1]);
    }
    bf16x8 bU[2][2];                     // [k-chunk c][n-tile t2]: UtT[t2*16+l15][c*32+q*8+j]
    #pragma unroll
    for (int c = 0; c < 2; ++c)
        #pragma unroll
        for (int t2 = 0; t2 < 2; ++t2) {
            const float4* p = (const float4*)(UtT + (t2 * 16 + l15) * WIDTH + c * 32 + quad * 8);
            bU[c][t2] = pack_bf8(p[0], p[1]);
        }
    // per-lane width set: w(t4,r) = t4*16 + quad*4 + r
    const float TWO_LOG2E = 2.8853900817779268f;
    float bt2[16], wu4[16];
    #pragma unroll
    for (int t4 = 0; t4 < 4; ++t4)
        #pragma unroll
        for (int r = 0; r < 4; ++r) {
            const int wdx = t4 * 16 + quad * 4 + r;
            bt2[t4 * 4 + r] = TWO_LOG2E * Bt[wdx];
            wu4[t4 * 4 + r] = 4.0f * wu[wdx];
        }

    const size_t gw = (size_t)blockIdx.x * 4 + wave;     // 0..8191, 128 rows each
    const float* zp = z + (gw * 128 + l15) * DD + quad * 8;

    float4 za = ((const float4*)zp)[0];
    float4 zb = ((const float4*)zp)[1];
    const f32x4 zero = {0.f, 0.f, 0.f, 0.f};

    for (int it = 0; it < 8; ++it) {
        float4 na = {0,0,0,0}, nb = {0,0,0,0};
        if (it < 7) {                                    // wave-uniform branch
            const float4* np = (const float4*)(zp + 16 * DD);
            na = np[0]; nb = np[1];
        }

        // ---- GEMM 1 (swapped): S^T = Wt @ z^T ----
        bf16x8 aZ = pack_bf8(za, zb);                    // as B-frag: B[k][n]=z[n][k]
        f32x4 accS[4];
        #pragma unroll
        for (int t4 = 0; t4 < 4; ++t4)
            accS[t4] = __builtin_amdgcn_mfma_f32_16x16x32_bf16(bW[t4], aZ, zero, 0, 0, 0);

        // ---- epilogue: tanh + trace partial + pack h per t4 ----
        float part = 0.f;
        unsigned P[4][2];
        #pragma unroll
        for (int t4 = 0; t4 < 4; ++t4) {
            bf16x4 hp;
            #pragma unroll
            for (int r = 0; r < 4; ++r) {
                const float f = fmaf(accS[t4][r], TWO_LOG2E, bt2[t4 * 4 + r]);
                const float e = exp2f(f);                        // e^(2s+2b), v_exp_f32
                const float u = __builtin_amdgcn_rcpf(e + 1.0f);
                const float h = fmaf(-2.0f, u, 1.0f);            // tanh(s+b)
                part = fmaf(fmaf(-u, u, u), wu4[t4 * 4 + r], part); // += (1-h^2)*wu/64
                hp[r] = (__bf16)h;
            }
            uint32x2 pp = __builtin_bit_cast(uint32x2, hp);
            P[t4][0] = pp[0]; P[t4][1] = pp[1];
        }

        // ---- quad exchange: (P[0],P[1]) -> aH0, (P[2],P[3]) -> aH1 ----
        auto w32a = __builtin_amdgcn_permlane32_swap(P[0][0], P[1][0], false, false);
        auto w32b = __builtin_amdgcn_permlane32_swap(P[0][1], P[1][1], false, false);
        auto w16a = __builtin_amdgcn_permlane16_swap(w32a[0], w32a[1], false, false);
        auto w16b = __builtin_amdgcn_permlane16_swap(w32b[0], w32b[1], false, false);
        uint32x4 u0 = {w16a[0], w16b[0], w16a[1], w16b[1]};
        bf16x8 aH0 = __builtin_bit_cast(bf16x8, u0);

        auto x32a = __builtin_amdgcn_permlane32_swap(P[2][0], P[3][0], false, false);
        auto x32b = __builtin_amdgcn_permlane32_swap(P[2][1], P[3][1], false, false);
        auto x16a = __builtin_amdgcn_permlane16_swap(x32a[0], x32a[1], false, false);
        auto x16b = __builtin_amdgcn_permlane16_swap(x32b[0], x32b[1], false, false);
        uint32x4 u1 = {x16a[0], x16b[0], x16a[1], x16b[1]};
        bf16x8 aH1 = __builtin_bit_cast(bf16x8, u1);

        // ---- GEMM 2 (swapped): dz^T = Ut^T @ h^T ----
        f32x4 accD[2];
        #pragma unroll
        for (int t2 = 0; t2 < 2; ++t2) {
            f32x4 cc = __builtin_amdgcn_mfma_f32_16x16x32_bf16(bU[0][t2], aH0, zero, 0, 0, 0);
            accD[t2] = __builtin_amdgcn_mfma_f32_16x16x32_bf16(bU[1][t2], aH1, cc, 0, 0, 0);
        }

        // ---- trace: quad reduce (HW-proven shfl_xor form) ----
        part += __shfl_xor(part, 16, 64);
        part += __shfl_xor(part, 32, 64);

        const size_t row0 = gw * 128 + (size_t)it * 16;
        if (quad == 0) dlogp[row0 + l15] = -part;      // 16 lanes, 64B coalesced

        // ---- dz stores: lane (l15,q) holds dz[row0+l15][16*t2+4q .. +3] -> float4 ----
        #pragma unroll
        for (int t2 = 0; t2 < 2; ++t2) {
            float4 v;
            v.x = accD[t2][0]; v.y = accD[t2][1]; v.z = accD[t2][2]; v.w = accD[t2][3];
            *(float4*)(dz + (row0 + l15) * DD + t2 * 16 + quad * 4) = v;
        }

        za = na; zb = nb;
        zp += 16 * DD;
    }
}

extern "C" void kernel_launch(void* const* d_in, const int* in_sizes, int n_in,
                              void* d_out, int out_size, void* d_ws, size_t ws_size,
                              hipStream_t stream)
{
    const float* t   = (const float*)d_in[0];
    const float* z   = (const float*)d_in[1];
    // d_in[2] = logp_z: unused by the reference outputs
    const float* Wc  = (const float*)d_in[3];
    const float* Wls = (const float*)d_in[4];
    const float* Ww  = (const float*)d_in[5];
    const float* Wb  = (const float*)d_in[6];
    const float* Uc  = (const float*)d_in[7];
    const float* Uls = (const float*)d_in[8];
    const float* Uw  = (const float*)d_in[9];
    const float* Ub  = (const float*)d_in[10];
    const float* Bc  = (const float*)d_in[11];
    const float* Bls = (const float*)d_in[12];
    const float* Bw  = (const float*)d_in[13];
    const float* Bb  = (const float*)d_in[14];

    float* wsWt  = (float*)d_ws;         // 2048  (Wt 64x32 row-major)
    float* wsUtT = wsWt + 2048;          // 2048  (Ut^T/64, 32x64)
    float* wsBt  = wsUtT + 2048;         // 64
    float* wswu  = wsBt + 64;            // 64   (wu/64)

    hyper_rows<<<16, 128, 0, stream>>>(t, Wc, Wls, Ww, Wb, Uc, Uls, Uw, Ub,
                                       Bc, Bls, Bw, Bb, wsWt, wsUtT, wsBt, wswu);

    float* dz = (float*)d_out;
    float* dlogp = dz + (size_t)BATCH_N * DD;
    cnf_main<<<2048, 256, 0, stream>>>(z, wsWt, wsUtT, wsBt, wswu, dz, dlogp);
}